// Round 6
// baseline (147.596 us; speedup 1.0000x reference)
//
#include <hip/hip_runtime.h>
#include <hip/hip_bf16.h>

// Binarized-weight conv2d: x[32][256][56][56] (f32), W[256][256][3][3] (sign)
// -> out[32][256][56][56] (f32), stride 1, pad 1.
// bf16 MFMA implicit GEMM. M=100352 px, N=256 c_out, K=2304.
// R6: R5's 8 micro-phases + REGISTER-LEVEL FRAGMENT PREFETCH: phase p reads
//     phase p+1's fragments before its barrier; MFMA waits only counted
//     lgkmcnt(3|8) for the PREVIOUS phase's reads. LDS transfer overlaps MFMA.
//     Stage->read distance 4-6 phases, uniform vmcnt(4); wf double-buffered.

#define N_IMG   32
#define C_IN    256
#define C_OUT   256
#define HW      56
#define HP      58
#define PIX     (HW*HW)      // 3136
#define M_TOT   (N_IMG*PIX)  // 100352
#define K_TOT   (C_IN*9)     // 2304

#define WB_BYTES   (C_OUT * K_TOT * 2)
#define XPAD_ELEMS (N_IMG * HP * HP * C_IN)
#define XPAD_BYTES (XPAD_ELEMS * 2)
#define WS_NEEDED  (WB_BYTES + XPAD_BYTES)

#define BM      224
#define NBLK    (M_TOT / BM)   // 448 = 8*56
#define NT      36             // K tiles of 64

typedef short  bf16x8 __attribute__((ext_vector_type(8)));
typedef float  f32x4  __attribute__((ext_vector_type(4)));

// ---------------- W binarize + reorder: OIHW f32 -> [co][khkw*256+ci] bf16 (+-1)
__global__ void __launch_bounds__(256) binW_kernel(const float* __restrict__ W,
                                                   unsigned short* __restrict__ wb) {
    int i = blockIdx.x * 256 + threadIdx.x;
    int co = i / K_TOT;
    int k  = i - co * K_TOT;
    int khkw = k >> 8;
    int ci   = k & 255;
    float v = W[co * K_TOT + ci * 9 + khkw];
    wb[i] = (v >= 0.f) ? 0x3F80u : 0xBF80u;
}

// ---------------- x: f32 NCHW -> bf16 NHWC padded [n][h+1][w+1][ci], halo fused
__global__ void __launch_bounds__(256) transpose_pad_kernel(const float* __restrict__ x,
                                                            unsigned short* __restrict__ xp) {
    __shared__ __align__(16) unsigned short s[HW * 258];
    const int t = threadIdx.x;
    const int h = blockIdx.x;
    const int n = blockIdx.y;
    const float* xrow = x + ((n * C_IN) * HW + h) * HW;

    #pragma unroll 4
    for (int i = 0; i < 64; ++i) {
        int idx = i * 256 + t;
        int ci = idx >> 6, w = idx & 63;
        if (w < HW) {
            float v = xrow[ci * PIX + w];
            __hip_bfloat16 b = __float2bfloat16(v);
            s[w * 258 + ci] = reinterpret_cast<unsigned short&>(b);
        }
    }
    __syncthreads();
    #pragma unroll 4
    for (int i = 0; i < 28; ++i) {
        int idx = i * 256 + t;
        int w = idx >> 7, cp = idx & 127;
        unsigned int d = *(const unsigned int*)&s[w * 258 + cp * 2];
        unsigned int off = ((n * HP + h + 1) * HP + (w + 1)) * C_IN + cp * 2;
        *(unsigned int*)&xp[off] = d;
    }
    // fused halo zeros (replaces global memset)
    if (t < 128) {
        *(unsigned int*)&xp[((n * HP + h + 1) * HP + 0)  * C_IN + t * 2] = 0u;
        *(unsigned int*)&xp[((n * HP + h + 1) * HP + 57) * C_IN + t * 2] = 0u;
    }
    if (h == 0) {
        unsigned int* row = (unsigned int*)&xp[(unsigned int)(n * HP + 0) * HP * C_IN];
        for (int i = t; i < HP * C_IN / 2; i += 256) row[i] = 0u;
    }
    if (h == HW - 1) {
        unsigned int* row = (unsigned int*)&xp[(unsigned int)(n * HP + 57) * HP * C_IN];
        for (int i = t; i < HP * C_IN / 2; i += 256) row[i] = 0u;
    }
}

// ---------------- GEMM: regions [parity][khalf] of [256 rows][32 k] = 16KB.
// X at XH, W at WH. swizzle: 16B chunk c of 64B row at physical c ^ ((row>>1)&3).
#define XH(b,s)  (((b)*2+(s))*16384)
#define WH(b,s)  (65536 + ((b)*2+(s))*16384)

__device__ __forceinline__ int xko(int kabs) {       // im2col offset into xpad
    int khkw = kabs >> 8;                            // 0..8 (uniform)
    int kh = (khkw * 11) >> 5;                       // /3 for 0..8
    int kw = khkw - kh * 3;
    return (kh * HP + kw) * C_IN + (kabs & 255);
}

__global__ void __launch_bounds__(512, 2)
conv_gemm_kernel(const __hip_bfloat16* __restrict__ xpad,
                 const __hip_bfloat16* __restrict__ wb,
                 float* __restrict__ out) {
    __shared__ __align__(16) unsigned short LDSBUF[65536];   // 128 KiB

    const int t    = threadIdx.x;
    const int lane = t & 63;
    const int wid  = t >> 6;
    const int wpx  = wid >> 2;       // 0..1 : 112-px half
    const int wco  = wid & 3;        // 0..3 : 64-co quarter
    const int l15  = lane & 15;
    const int l4   = lane >> 4;

    int bid = (int)blockIdx.x;
    bid = (bid & 7) * (NBLK / 8) + (bid >> 3);      // XCD swizzle (448 = 8*56)
    const int m0 = bid * BM;

    // read-side LDS byte offsets (within one 16KB region)
    int xrd[7], wrd[4];
    #pragma unroll
    for (int i = 0; i < 7; ++i) {
        int r = wpx * 112 + i * 16 + l15;
        xrd[i] = r * 64 + ((l4 ^ ((r >> 1) & 3)) << 4);
    }
    #pragma unroll
    for (int j = 0; j < 4; ++j) {
        int r = wco * 64 + j * 16 + l15;
        wrd[j] = r * 64 + ((l4 ^ ((r >> 1) & 3)) << 4);
    }

    // stage-side: issue0 -> rows 0..127 (dest t*16), issue1 -> rows 128..255 (+8192)
    const int lc8 = ((t & 3) ^ ((t >> 3) & 3)) << 3;     // inverse-swizzled k offset (elems)
    int rbA, rbB;
    {
        int rA = t >> 2;
        int rB = 128 + rA; if (rB > BM - 1) rB = BM - 1;   // rows 224..255: dup, never read
        int mA = m0 + rA, mB = m0 + rB;
        int nA = mA / PIX, pA = mA - nA * PIX, hA = pA / HW, wA = pA - hA * HW;
        int nB = mB / PIX, pB = mB - nB * PIX, hB = pB / HW, wB2 = pB - hB * HW;
        rbA = ((nA * HP + hA) * HP + wA) * C_IN + lc8;
        rbB = ((nB * HP + hB) * HP + wB2) * C_IN + lc8;
    }
    int wgA, wgB;
    {
        int rA = t >> 2;
        wgA = rA * K_TOT + lc8;
        wgB = (128 + rA) * K_TOT + lc8;
    }

#define GLD(gp, off) __builtin_amdgcn_global_load_lds( \
        (const __attribute__((address_space(1))) void*)(gp), \
        (__attribute__((address_space(3))) void*)((char*)LDSBUF + (off)), 16, 0, 0)
#define STGX(b,s,ko) { GLD(xpad + rbA + (ko), XH(b,s) + t * 16); \
                       GLD(xpad + rbB + (ko), XH(b,s) + 8192 + t * 16); }
#define STGW(b,s,ka) { GLD(wb + wgA + (ka), WH(b,s) + t * 16); \
                       GLD(wb + wgB + (ka), WH(b,s) + 8192 + t * 16); }
#define LDXF(i,b,s)  (*(const bf16x8*)((const char*)LDSBUF + XH(b,s) + xrd[i]))
#define LDWF(j,b,s)  (*(const bf16x8*)((const char*)LDSBUF + WH(b,s) + wrd[j]))

    f32x4 acc[7][4];
    #pragma unroll
    for (int i = 0; i < 7; ++i)
        #pragma unroll
        for (int j = 0; j < 4; ++j)
            acc[i][j] = (f32x4){0.f, 0.f, 0.f, 0.f};

    bf16x8 xa[4], xb[3], wf0[4], wf1[4];

    // PH_A(b,s): prefetch xb frags 4-6 of SAME (b,s) (3 ds_reads), stage,
    //   lgkmcnt(3) [= previous phase's 8 reads done], barrier, 16 MFMA (xa,WFU).
    // PH_B(b,s -> bn,sn): prefetch next pair's xa+WFD (8 ds_reads), stage,
    //   lgkmcnt(8) [= previous phase's 3 reads done], barrier, 12 MFMA (xb,WFU).
    // The current phase's prefetch transfers during its own barrier+MFMA window.
#define SYNC_MID(NLG) \
        asm volatile("s_waitcnt lgkmcnt(" #NLG ")" ::: "memory"); \
        __builtin_amdgcn_sched_barrier(0); \
        __builtin_amdgcn_s_barrier(); \
        __builtin_amdgcn_sched_barrier(0)
#define SYNC_BOT \
        asm volatile("s_waitcnt vmcnt(4)" ::: "memory"); \
        __builtin_amdgcn_sched_barrier(0)

#define PH_A(b, s, WFU, STGE) { \
        xb[0]=LDXF(4,b,s); xb[1]=LDXF(5,b,s); xb[2]=LDXF(6,b,s); \
        STGE; \
        SYNC_MID(3); \
        __builtin_amdgcn_s_setprio(1); \
        _Pragma("unroll") \
        for (int i_ = 0; i_ < 4; ++i_) \
            _Pragma("unroll") \
            for (int j_ = 0; j_ < 4; ++j_) \
                acc[i_][j_] = __builtin_amdgcn_mfma_f32_16x16x32_bf16(WFU[j_], xa[i_], acc[i_][j_], 0, 0, 0); \
        __builtin_amdgcn_s_setprio(0); \
        SYNC_BOT; \
    }

#define PH_B(b, s, WFU, bn, sn, WFD, STGE) { \
        xa[0]=LDXF(0,bn,sn); xa[1]=LDXF(1,bn,sn); xa[2]=LDXF(2,bn,sn); xa[3]=LDXF(3,bn,sn); \
        WFD[0]=LDWF(0,bn,sn); WFD[1]=LDWF(1,bn,sn); WFD[2]=LDWF(2,bn,sn); WFD[3]=LDWF(3,bn,sn); \
        STGE; \
        SYNC_MID(8); \
        __builtin_amdgcn_s_setprio(1); \
        _Pragma("unroll") \
        for (int i_ = 0; i_ < 3; ++i_) \
            _Pragma("unroll") \
            for (int j_ = 0; j_ < 4; ++j_) \
                acc[4 + i_][j_] = __builtin_amdgcn_mfma_f32_16x16x32_bf16(WFU[j_], xb[i_], acc[4 + i_][j_], 0, 0, 0); \
        __builtin_amdgcn_s_setprio(0); \
        SYNC_BOT; \
    }

    // prologue: stage T0 both halves + T1 half0 (6 regions, 12 GLD); drain;
    // then read pair(0,0)'s A-frags into xa/wf0.
    {
        int ko00 = xko(0), ko01 = xko(32), ko10 = xko(64);
        STGX(0, 0, ko00); STGW(0, 0, 0);
        STGX(0, 1, ko01); STGW(0, 1, 32);
        STGX(1, 0, ko10); STGW(1, 0, 64);
    }
    asm volatile("s_waitcnt vmcnt(0)" ::: "memory");
    __builtin_amdgcn_sched_barrier(0);
    __builtin_amdgcn_s_barrier();
    __builtin_amdgcn_sched_barrier(0);
    xa[0]=LDXF(0,0,0); xa[1]=LDXF(1,0,0); xa[2]=LDXF(2,0,0); xa[3]=LDXF(3,0,0);
    wf0[0]=LDWF(0,0,0); wf0[1]=LDWF(1,0,0); wf0[2]=LDWF(2,0,0); wf0[3]=LDWF(3,0,0);

    // stage map (distance stage->first-read = 4..6 phases, vmcnt(4)/phase):
    // p1:X(1,1)<-T1k1  p2:W(1,1)<-T1k1  p3:X(0,0)<-T2k0  p4:W(0,0)<-T2k0
    // p5:X(0,1)<-T2k1  p6:W(0,1)<-T2k1  p7:X(1,0)<-T3k0  p8:W(1,0)<-T3k0
    #pragma unroll 1
    for (int it = 0; it < NT / 2; ++it) {
        const int T1 = 2 * it + 1;
        int T2 = 2 * it + 2; if (T2 > NT - 1) T2 = NT - 1;   // clamped over-stage
        int T3 = 2 * it + 3; if (T3 > NT - 1) T3 = NT - 1;

        PH_A(0, 0, wf0, STGX(1, 1, xko(T1 * 64 + 32)));       // p1
        PH_B(0, 0, wf0, 0, 1, wf1, STGW(1, 1, T1 * 64 + 32)); // p2
        PH_A(0, 1, wf1, STGX(0, 0, xko(T2 * 64)));            // p3
        PH_B(0, 1, wf1, 1, 0, wf0, STGW(0, 0, T2 * 64));      // p4
        PH_A(1, 0, wf0, STGX(0, 1, xko(T2 * 64 + 32)));       // p5
        PH_B(1, 0, wf0, 1, 1, wf1, STGW(0, 1, T2 * 64 + 32)); // p6
        PH_A(1, 1, wf1, STGX(1, 0, xko(T3 * 64)));            // p7
        PH_B(1, 1, wf1, 0, 0, wf0, STGW(1, 0, T3 * 64));      // p8
    }
    asm volatile("s_waitcnt vmcnt(0)" ::: "memory");   // drain stage GLDs pre-endpgm

    // epilogue: C row=co (l4*4+r), col=px (l15)
    const int nimg = m0 / PIX;                // exact: 3136 = 14*224
    const int p0   = m0 - nimg * PIX;
    float* ob = out + nimg * (C_OUT * PIX);
    #pragma unroll
    for (int i = 0; i < 7; ++i) {
        int p = p0 + wpx * 112 + i * 16 + l15;
        #pragma unroll
        for (int j = 0; j < 4; ++j) {
            int co = wco * 64 + j * 16 + l4 * 4;
            #pragma unroll
            for (int r = 0; r < 4; ++r)
                ob[(co + r) * PIX + p] = acc[i][j][r];
        }
    }
#undef PH_A
#undef PH_B
#undef SYNC_MID
#undef SYNC_BOT
#undef GLD
#undef STGX
#undef STGW
#undef LDXF
#undef LDWF
}

// ---------------- fallback: naive direct conv
__global__ void __launch_bounds__(256) conv_naive_kernel(const float* __restrict__ x,
                                                         const float* __restrict__ W,
                                                         float* __restrict__ out) {
    int idx = blockIdx.x * 256 + threadIdx.x;
    int w = idx % HW;
    int tmp = idx / HW;
    int h = tmp % HW;
    tmp /= HW;
    int co = tmp & 255;
    int n  = tmp >> 8;
    const float* xn = x + n * (C_IN * PIX);
    const float* wc = W + co * K_TOT;
    float acc = 0.f;
    for (int ci = 0; ci < C_IN; ++ci) {
        const float* xc = xn + ci * PIX;
        const float* wk = wc + ci * 9;
        #pragma unroll
        for (int kh = 0; kh < 3; ++kh) {
            int hh = h + kh - 1;
            if (hh < 0 || hh >= HW) continue;
            #pragma unroll
            for (int kw = 0; kw < 3; ++kw) {
                int ww = w + kw - 1;
                if (ww < 0 || ww >= HW) continue;
                float xv = xc[hh * HW + ww];
                acc += (wk[kh * 3 + kw] >= 0.f) ? xv : -xv;
            }
        }
    }
    out[idx] = acc;
}

extern "C" void kernel_launch(void* const* d_in, const int* in_sizes, int n_in,
                              void* d_out, int out_size, void* d_ws, size_t ws_size,
                              hipStream_t stream) {
    const float* x = (const float*)d_in[0];
    const float* W = (const float*)d_in[1];
    float* out = (float*)d_out;

    if (ws_size < (size_t)WS_NEEDED) {
        int total = N_IMG * C_OUT * PIX;
        conv_naive_kernel<<<(total + 255) / 256, 256, 0, stream>>>(x, W, out);
        return;
    }

    unsigned short* wb   = (unsigned short*)d_ws;
    __hip_bfloat16* xpad = (__hip_bfloat16*)((char*)d_ws + WB_BYTES);

    binW_kernel<<<(C_OUT * K_TOT) / 256, 256, 0, stream>>>(W, wb);
    transpose_pad_kernel<<<dim3(HW, N_IMG), 256, 0, stream>>>(x, (unsigned short*)xpad);
    conv_gemm_kernel<<<dim3(NBLK), 512, 0, stream>>>(xpad, (const __hip_bfloat16*)wb, out);
}

// Round 7
// 103.681 us; speedup vs baseline: 1.4236x; 1.4236x over previous
//
#include <hip/hip_runtime.h>
#include <hip/hip_bf16.h>

// Binarized-weight conv2d: x[32][256][56][56] (f32), W[256][256][3][3] (sign)
// -> out[32][256][56][56] (f32), stride 1, pad 1.
// R7: INT8 implicit GEMM. W in {+1,-1} i8 (exact); X quantized i8 with fixed
//     scale C=5.5 (err absmax ~3.5 << 5.16 threshold). mfma_i32_16x16x64_i8:
//     2x OPS/instr and 2x K per fragment byte vs bf16 -> both MFMA and LDS
//     floors halve. Region = [256 rows][64B] = full K-tile now; byte-level
//     swizzle/staging identical to R5. 4-deep tile buffers, vmcnt(8) BEFORE
//     the mid-phase barrier (retire -> barrier -> dependent reads).

#define N_IMG   32
#define C_IN    256
#define C_OUT   256
#define HW      56
#define HP      58
#define PIX     (HW*HW)      // 3136
#define M_TOT   (N_IMG*PIX)  // 100352
#define K_TOT   (C_IN*9)     // 2304

#define WQ_BYTES   (C_OUT * K_TOT)                 // 589824
#define XPAD_BYTES (N_IMG * HP * HP * C_IN)        // 27,557,888
#define WS_NEEDED  (WQ_BYTES + XPAD_BYTES)

#define BM      224
#define NBLK    (M_TOT / BM)   // 448 = 8*56
#define NT      36             // K tiles of 64

#define QCLIP   5.5f

typedef int   i32x4 __attribute__((ext_vector_type(4)));

// ---------------- W binarize + reorder: OIHW f32 -> [co][khkw*256+ci] i8 (+-1)
__global__ void __launch_bounds__(256) binW_kernel(const float* __restrict__ W,
                                                   unsigned int* __restrict__ wq4) {
    int i4 = blockIdx.x * 256 + threadIdx.x;         // over 147456
    int base = i4 * 4;
    int co = base / K_TOT;
    int k  = base - co * K_TOT;
    int khkw = k >> 8;
    int ci   = k & 255;
    const float* wp = W + co * K_TOT + ci * 9 + khkw;
    unsigned int pk = 0;
    #pragma unroll
    for (int j = 0; j < 4; ++j) {
        unsigned int b = (wp[j * 9] >= 0.f) ? 0x01u : 0xFFu;
        pk |= b << (8 * j);
    }
    wq4[i4] = pk;
}

// ---------------- x: f32 NCHW -> i8 NHWC padded [n][h+1][w+1][ci], halo fused
__global__ void __launch_bounds__(256) transpose_pad_kernel(const float* __restrict__ x,
                                                            signed char* __restrict__ xp) {
    __shared__ __align__(4) signed char s[HW * 260];   // stride 260B = 65 dwords (odd)
    const int t = threadIdx.x;
    const int h = blockIdx.x;
    const int n = blockIdx.y;
    const float* xrow = x + ((n * C_IN) * HW + h) * HW;
    const float QI = 127.0f / QCLIP;

    #pragma unroll 4
    for (int i = 0; i < 64; ++i) {
        int idx = i * 256 + t;
        int ci = idx >> 6, w = idx & 63;
        if (w < HW) {
            int q = __float2int_rn(xrow[ci * PIX + w] * QI);
            q = q > 127 ? 127 : (q < -127 ? -127 : q);
            s[w * 260 + ci] = (signed char)q;
        }
    }
    __syncthreads();
    unsigned int* xp32 = (unsigned int*)xp;
    #pragma unroll 4
    for (int i = 0; i < 14; ++i) {
        int idx = i * 256 + t;                        // dword over 56*64
        int w = idx >> 6, cq = idx & 63;
        unsigned int d = *(const unsigned int*)&s[w * 260 + cq * 4];
        xp32[((n * HP + h + 1) * HP + (w + 1)) * 64 + cq] = d;
    }
    // fused halo zeros
    if (t < 64) {
        xp32[((n * HP + h + 1) * HP + 0)  * 64 + t] = 0u;
        xp32[((n * HP + h + 1) * HP + 57) * 64 + t] = 0u;
    }
    if (h == 0) {
        unsigned int* row = xp32 + (unsigned int)(n * HP + 0) * HP * 64;
        for (int i = t; i < HP * 64; i += 256) row[i] = 0u;
    }
    if (h == HW - 1) {
        unsigned int* row = xp32 + (unsigned int)(n * HP + 57) * HP * 64;
        for (int i = t; i < HP * 64; i += 256) row[i] = 0u;
    }
}

// ---------------- i8 GEMM: 4 tile-buffers, region [256 rows][64B] = 16KB.
// X regions at XS(b), W at WS(b). swizzle: 16B chunk c of 64B row at c^((row>>1)&3).
#define XS(b)  ((b)*16384)
#define WS(b)  (65536 + (b)*16384)

__device__ __forceinline__ int xko(int kabs) {       // im2col offset into xpad (i8)
    int khkw = kabs >> 8;                            // 0..8 (uniform)
    int kh = (khkw * 11) >> 5;                       // /3 for 0..8
    int kw = khkw - kh * 3;
    return (kh * HP + kw) * C_IN + (kabs & 255);
}

__global__ void __launch_bounds__(512, 2)
conv_gemm_kernel(const signed char* __restrict__ xpad,
                 const signed char* __restrict__ wq,
                 float* __restrict__ out) {
    __shared__ __align__(16) signed char LDSBUF[131072];   // 128 KiB

    const int t    = threadIdx.x;
    const int lane = t & 63;
    const int wid  = t >> 6;
    const int wpx  = wid >> 2;       // 0..1 : 112-px half
    const int wco  = wid & 3;        // 0..3 : 64-co quarter
    const int l15  = lane & 15;
    const int l4   = lane >> 4;      // k-group: 16 i8 each (K=64 per region row)

    int bid = (int)blockIdx.x;
    bid = (bid & 7) * (NBLK / 8) + (bid >> 3);      // XCD swizzle (448 = 8*56)
    const int m0 = bid * BM;

    // read-side LDS byte offsets (within one 16KB region)
    int xrd[7], wrd[4];
    #pragma unroll
    for (int i = 0; i < 7; ++i) {
        int r = wpx * 112 + i * 16 + l15;
        xrd[i] = r * 64 + ((l4 ^ ((r >> 1) & 3)) << 4);
    }
    #pragma unroll
    for (int j = 0; j < 4; ++j) {
        int r = wco * 64 + j * 16 + l15;
        wrd[j] = r * 64 + ((l4 ^ ((r >> 1) & 3)) << 4);
    }

    // stage-side: issue0 -> rows 0..127 (dest t*16), issue1 -> rows 128..255 (+8192)
    const int lc16 = ((t & 3) ^ ((t >> 3) & 3)) << 4;    // inverse-swizzled k offset (i8)
    int rbA, rbB;
    {
        int rA = t >> 2;
        int rB = 128 + rA; if (rB > BM - 1) rB = BM - 1;   // rows 224..255: dup, never read
        int mA = m0 + rA, mB = m0 + rB;
        int nA = mA / PIX, pA = mA - nA * PIX, hA = pA / HW, wA = pA - hA * HW;
        int nB = mB / PIX, pB = mB - nB * PIX, hB = pB / HW, wB2 = pB - hB * HW;
        rbA = ((nA * HP + hA) * HP + wA) * C_IN + lc16;
        rbB = ((nB * HP + hB) * HP + wB2) * C_IN + lc16;
    }
    int wgA, wgB;
    {
        int rA = t >> 2;
        wgA = rA * K_TOT + lc16;
        wgB = (128 + rA) * K_TOT + lc16;
    }

#define GLD(gp, off) __builtin_amdgcn_global_load_lds( \
        (const __attribute__((address_space(1))) void*)(gp), \
        (__attribute__((address_space(3))) void*)(LDSBUF + (off)), 16, 0, 0)
#define STGX(b,ko) { GLD(xpad + rbA + (ko), XS(b) + t * 16); \
                     GLD(xpad + rbB + (ko), XS(b) + 8192 + t * 16); }
#define STGW(b,ka) { GLD(wq + wgA + (ka), WS(b) + t * 16); \
                     GLD(wq + wgB + (ka), WS(b) + 8192 + t * 16); }
#define LDXF(i,b)  (*(const i32x4*)(LDSBUF + XS(b) + xrd[i]))
#define LDWF(j,b)  (*(const i32x4*)(LDSBUF + WS(b) + wrd[j]))

    i32x4 acc[7][4];
    #pragma unroll
    for (int i = 0; i < 7; ++i)
        #pragma unroll
        for (int j = 0; j < 4; ++j)
            acc[i][j] = (i32x4){0, 0, 0, 0};

    i32x4 wf[4];   // W frags: read in PH_A, reused in PH_B

    // Tile T lives in buffer T&3 (X and W regions). While computing T we stage
    // tile T+3 into buffer (T+3)&3 (X half in PH_A, W half in PH_B).
    // PH_B's vmcnt(8) sits BEFORE its mid barrier: outstanding there =
    // {T-2:4, T-1:4, T:4} = 12 -> retires the 4 oldest = tile T+1's stages,
    // two barriers before PH_A(T+1) reads them. Restage of buffer (T+3)&3
    // happens after the end-barrier of PH_B(T-1), by which point every wave's
    // lgkmcnt(0) has completed its reads of tile T-1 (same buffer).  [safe]
#define PH_A(b, koX) { \
        i32x4 xf[4]; \
        xf[0]=LDXF(0,b); xf[1]=LDXF(1,b); xf[2]=LDXF(2,b); xf[3]=LDXF(3,b); \
        wf[0]=LDWF(0,b); wf[1]=LDWF(1,b); wf[2]=LDWF(2,b); wf[3]=LDWF(3,b); \
        STGX(((b)+3)&3, koX); \
        __builtin_amdgcn_sched_barrier(0); \
        __builtin_amdgcn_s_barrier(); \
        asm volatile("s_waitcnt lgkmcnt(0)" ::: "memory"); \
        __builtin_amdgcn_sched_barrier(0); \
        __builtin_amdgcn_s_setprio(1); \
        _Pragma("unroll") \
        for (int i_ = 0; i_ < 4; ++i_) \
            _Pragma("unroll") \
            for (int j_ = 0; j_ < 4; ++j_) \
                acc[i_][j_] = __builtin_amdgcn_mfma_i32_16x16x64_i8(wf[j_], xf[i_], acc[i_][j_], 0, 0, 0); \
        __builtin_amdgcn_s_setprio(0); \
        __builtin_amdgcn_sched_barrier(0); \
        __builtin_amdgcn_s_barrier(); \
        __builtin_amdgcn_sched_barrier(0); \
    }

#define PH_B(b, kaW) { \
        i32x4 xf[3]; \
        xf[0]=LDXF(4,b); xf[1]=LDXF(5,b); xf[2]=LDXF(6,b); \
        STGW(((b)+3)&3, kaW); \
        asm volatile("s_waitcnt vmcnt(8)" ::: "memory"); \
        __builtin_amdgcn_sched_barrier(0); \
        __builtin_amdgcn_s_barrier(); \
        asm volatile("s_waitcnt lgkmcnt(0)" ::: "memory"); \
        __builtin_amdgcn_sched_barrier(0); \
        __builtin_amdgcn_s_setprio(1); \
        _Pragma("unroll") \
        for (int i_ = 0; i_ < 3; ++i_) \
            _Pragma("unroll") \
            for (int j_ = 0; j_ < 4; ++j_) \
                acc[4 + i_][j_] = __builtin_amdgcn_mfma_i32_16x16x64_i8(wf[j_], xf[i_], acc[4 + i_][j_], 0, 0, 0); \
        __builtin_amdgcn_s_setprio(0); \
        __builtin_amdgcn_sched_barrier(0); \
        __builtin_amdgcn_s_barrier(); \
        __builtin_amdgcn_sched_barrier(0); \
    }

    // prologue: stage tiles 0,1,2 (12 GLD); vmcnt(8) retires tile0; barrier.
    STGX(0, xko(0));   STGW(0, 0);
    STGX(1, xko(64));  STGW(1, 64);
    STGX(2, xko(128)); STGW(2, 128);
    asm volatile("s_waitcnt vmcnt(8)" ::: "memory");
    __builtin_amdgcn_sched_barrier(0);
    __builtin_amdgcn_s_barrier();
    __builtin_amdgcn_sched_barrier(0);

    #pragma unroll 1
    for (int it = 0; it < 9; ++it) {
        const int Tb = 4 * it;
        int T0 = Tb + 3; if (T0 > NT - 1) T0 = NT - 1;   // clamped over-stage
        int T1 = Tb + 4; if (T1 > NT - 1) T1 = NT - 1;
        int T2 = Tb + 5; if (T2 > NT - 1) T2 = NT - 1;
        int T3 = Tb + 6; if (T3 > NT - 1) T3 = NT - 1;

        PH_A(0, xko(T0 * 64)); PH_B(0, T0 * 64);
        PH_A(1, xko(T1 * 64)); PH_B(1, T1 * 64);
        PH_A(2, xko(T2 * 64)); PH_B(2, T2 * 64);
        PH_A(3, xko(T3 * 64)); PH_B(3, T3 * 64);
    }
    asm volatile("s_waitcnt vmcnt(0)" ::: "memory");   // drain stage GLDs

    // epilogue: C row=co (l4*4+r), col=px (l15); dequant by C/127
    const float QS = QCLIP / 127.0f;
    const int nimg = m0 / PIX;                // exact: 3136 = 14*224
    const int p0   = m0 - nimg * PIX;
    float* ob = out + nimg * (C_OUT * PIX);
    #pragma unroll
    for (int i = 0; i < 7; ++i) {
        int p = p0 + wpx * 112 + i * 16 + l15;
        #pragma unroll
        for (int j = 0; j < 4; ++j) {
            int co = wco * 64 + j * 16 + l4 * 4;
            #pragma unroll
            for (int r = 0; r < 4; ++r)
                ob[(co + r) * PIX + p] = (float)acc[i][j][r] * QS;
        }
    }
#undef PH_A
#undef PH_B
#undef GLD
#undef STGX
#undef STGW
#undef LDXF
#undef LDWF
}

// ---------------- fallback: naive direct conv
__global__ void __launch_bounds__(256) conv_naive_kernel(const float* __restrict__ x,
                                                         const float* __restrict__ W,
                                                         float* __restrict__ out) {
    int idx = blockIdx.x * 256 + threadIdx.x;
    int w = idx % HW;
    int tmp = idx / HW;
    int h = tmp % HW;
    tmp /= HW;
    int co = tmp & 255;
    int n  = tmp >> 8;
    const float* xn = x + n * (C_IN * PIX);
    const float* wc = W + co * K_TOT;
    float acc = 0.f;
    for (int ci = 0; ci < C_IN; ++ci) {
        const float* xc = xn + ci * PIX;
        const float* wk = wc + ci * 9;
        #pragma unroll
        for (int kh = 0; kh < 3; ++kh) {
            int hh = h + kh - 1;
            if (hh < 0 || hh >= HW) continue;
            #pragma unroll
            for (int kw = 0; kw < 3; ++kw) {
                int ww = w + kw - 1;
                if (ww < 0 || ww >= HW) continue;
                float xv = xc[hh * HW + ww];
                acc += (wk[kh * 3 + kw] >= 0.f) ? xv : -xv;
            }
        }
    }
    out[idx] = acc;
}

extern "C" void kernel_launch(void* const* d_in, const int* in_sizes, int n_in,
                              void* d_out, int out_size, void* d_ws, size_t ws_size,
                              hipStream_t stream) {
    const float* x = (const float*)d_in[0];
    const float* W = (const float*)d_in[1];
    float* out = (float*)d_out;

    if (ws_size < (size_t)WS_NEEDED) {
        int total = N_IMG * C_OUT * PIX;
        conv_naive_kernel<<<(total + 255) / 256, 256, 0, stream>>>(x, W, out);
        return;
    }

    unsigned int* wq4   = (unsigned int*)d_ws;
    signed char*  xpad  = (signed char*)d_ws + WQ_BYTES;

    binW_kernel<<<(WQ_BYTES / 4) / 256, 256, 0, stream>>>(W, wq4);
    transpose_pad_kernel<<<dim3(HW, N_IMG), 256, 0, stream>>>(x, xpad);
    conv_gemm_kernel<<<dim3(NBLK), 512, 0, stream>>>(xpad, (const signed char*)wq4, out);
}